// Round 6
// baseline (424.697 us; speedup 1.0000x reference)
//
#include <hip/hip_runtime.h>
#include <stdint.h>

// ---- problem constants ----
#define B_    2
#define S_    2048
#define DIM_  2048
#define H_    16
#define KVH_  4
#define HD_   128
#define NTOK  (B_*S_)   // 4096
#define NQKV  3072      // H*HD + 2*KVH*HD

typedef unsigned short u16;
typedef unsigned int u32a __attribute__((may_alias));
typedef short bf16x8 __attribute__((ext_vector_type(8), may_alias));
typedef float f32x4 __attribute__((ext_vector_type(4), may_alias));
typedef unsigned short u16x8 __attribute__((ext_vector_type(8), may_alias));
typedef unsigned short u16x4 __attribute__((ext_vector_type(4), may_alias));

__device__ __forceinline__ float bf2f(u16 v) {
    unsigned u = (unsigned)v << 16;
    return __builtin_bit_cast(float, u);
}
__device__ __forceinline__ u16 f2bf(float f) {
    unsigned u = __builtin_bit_cast(unsigned, f);
    unsigned r = (u + 0x7fffu + ((u >> 16) & 1u)) >> 16;  // RNE
    return (u16)r;
}
__device__ __forceinline__ unsigned cvt_pk_bf16(float lo, float hi) {
    unsigned r;
    asm("v_cvt_pk_bf16_f32 %0, %1, %2" : "=v"(r) : "v"(lo), "v"(hi));
    return r;
}

#if __has_builtin(__builtin_amdgcn_exp2f)
#define EXP2(x) __builtin_amdgcn_exp2f(x)
#else
#define EXP2(x) exp2f(x)
#endif

__device__ __forceinline__ void gload_lds16(const void* g, void* l) {
    __builtin_amdgcn_global_load_lds(
        (const __attribute__((address_space(1))) void*)g,
        (__attribute__((address_space(3))) void*)l, 16, 0, 0);
}

__device__ __forceinline__ f32x4 zero4() { f32x4 z = {0.f, 0.f, 0.f, 0.f}; return z; }

// ---- fp32 -> bf16 convert (vectorized) ----
__global__ void cvt_f32_bf16(const float* __restrict__ src, u16* __restrict__ dst, int n4) {
    int i = blockIdx.x * blockDim.x + threadIdx.x;
    int stride = gridDim.x * blockDim.x;
    for (; i < n4; i += stride) {
        float4 v = ((const float4*)src)[i];
        u16x4 o;
        o[0] = f2bf(v.x); o[1] = f2bf(v.y); o[2] = f2bf(v.z); o[3] = f2bf(v.w);
        ((u16x4*)dst)[i] = o;
    }
}

// ---- bf16 NT GEMM: C[M][N] = A[M][K] * Bt[N][K]^T ----
// 128x128 tile, BK=64, 4 waves (2x2), m97-style 2-barrier K-loop.
// MODE 0: plain fp32 C write. MODE 1: QKV epilogue — RoPE on Q (in-place
// layout in xqkv) and K (scattered to xk (b,g,pos,d)), V plain bf16 to xqkv.
template <int MODE>
__global__ __launch_bounds__(256) void gemm_nt(const u16* __restrict__ A,
                                               const u16* __restrict__ Bt,
                                               void* __restrict__ C,
                                               u16* __restrict__ xk,
                                               const float* __restrict__ fcos,
                                               const float* __restrict__ fsin,
                                               int M, int N, int K) {
    __shared__ u16 As[128 * 64];
    __shared__ u16 Bs[128 * 64];
    int tid = threadIdx.x;
    int m0 = blockIdx.y * 128, n0 = blockIdx.x * 128;
    int lane = tid & 63, lg = lane >> 4, ln = lane & 15;
    int w = tid >> 6, wr = w >> 1, wc = w & 1;

    f32x4 acc[4][4];
#pragma unroll
    for (int i = 0; i < 4; i++)
#pragma unroll
        for (int j = 0; j < 4; j++) acc[i][j] = zero4();

    int nk = K >> 6;
    for (int kt = 0; kt < nk; kt++) {
        int k0 = kt << 6;
#pragma unroll
        for (int i = 0; i < 4; i++) {  // A tile: 128 rows x 64 cols bf16
            int flat = i * 256 + tid;
            int row = flat >> 3, c16 = flat & 7;
            gload_lds16(A + (m0 + row) * K + k0 + c16 * 8, &As[flat * 8]);
        }
#pragma unroll
        for (int i = 0; i < 4; i++) {  // B tile
            int flat = i * 256 + tid;
            int row = flat >> 3, c16 = flat & 7;
            gload_lds16(Bt + (n0 + row) * K + k0 + c16 * 8, &Bs[flat * 8]);
        }
        __syncthreads();  // drains vmcnt before reads

        bf16x8 af[4][2], bfr[4][2];
#pragma unroll
        for (int mf = 0; mf < 4; mf++)
#pragma unroll
            for (int kk = 0; kk < 2; kk++)
                af[mf][kk] = *(const bf16x8*)&As[(wr * 64 + mf * 16 + ln) * 64 + kk * 32 + lg * 8];
#pragma unroll
        for (int nf = 0; nf < 4; nf++)
#pragma unroll
            for (int kk = 0; kk < 2; kk++)
                bfr[nf][kk] = *(const bf16x8*)&Bs[(wc * 64 + nf * 16 + ln) * 64 + kk * 32 + lg * 8];
#pragma unroll
        for (int kk = 0; kk < 2; kk++)
#pragma unroll
            for (int mf = 0; mf < 4; mf++)
#pragma unroll
                for (int nf = 0; nf < 4; nf++)
                    acc[mf][nf] = __builtin_amdgcn_mfma_f32_16x16x32_bf16(
                        af[mf][kk], bfr[nf][kk], acc[mf][nf], 0, 0, 0);
        __syncthreads();  // before next overwrite
    }

    // epilogue: C fragment layout row=(lane>>4)*4+reg, col=lane&15 per 16x16
#pragma unroll
    for (int mf = 0; mf < 4; mf++)
#pragma unroll
        for (int nf = 0; nf < 4; nf++) {
            int colbase = n0 + wc * 64 + nf * 16;  // wave-uniform
            int rowbase = m0 + wr * 64 + mf * 16 + lg * 4;
#pragma unroll
            for (int r = 0; r < 4; r++) {
                int row = rowbase + r;
                int col = colbase + ln;
                float v = acc[mf][nf][r];
                if (MODE == 0) {
                    ((float*)C)[row * N + col] = v;
                } else {
                    float outv = v;
                    if (colbase < 2560) {  // Q or K: RoPE (pair partner = lane^1)
                        float p = __shfl_xor(v, 1);
                        int pos = row & (S_ - 1);
                        int j = (col & 127) >> 1;
                        float c = fcos[pos * 64 + j];
                        float s = fsin[pos * 64 + j];
                        float ss = (ln & 1) ? s : -s;
                        outv = v * c + p * ss;
                    }
                    if (colbase < 2048) {          // Q -> xqkv in place
                        ((u16*)C)[row * N + col] = f2bf(outv);
                    } else if (colbase < 2560) {   // K -> xk (b,g,pos,d)
                        int cc = col - 2048;
                        int gg = cc >> 7, d = cc & 127;
                        int b = row >> 11, pos = row & (S_ - 1);
                        xk[((b * KVH_ + gg) * S_ + pos) * HD_ + d] = f2bf(outv);
                    } else {                       // V -> xqkv
                        ((u16*)C)[row * N + col] = f2bf(outv);
                    }
                }
            }
        }
}

// ---- V transpose: xqkv V cols -> vt (b,g,d,pos) bf16 ----
__global__ void vtrans(const u16* __restrict__ xqkv, u16* __restrict__ vt) {
    int tid = threadIdx.x;
    int blk = blockIdx.x;           // bg * 128 + ptile
    int ptile = blk & 127;          // S/16 = 128
    int bg = blk >> 7;              // 0..7
    int b = bg >> 2, gg = bg & 3;
    int d = tid & 127, pg = tid >> 7;
    int pos0 = ptile * 16 + pg * 8;
    u16x8 v;
#pragma unroll
    for (int i = 0; i < 8; i++)
        v[i] = xqkv[(b * S_ + pos0 + i) * NQKV + 2560 + gg * HD_ + d];  // coalesced over d
    *(u16x8*)(vt + (bg * HD_ + d) * S_ + pos0) = v;
}

// ---- flash attention v3: swapped QK^T, async double-buffered K/V staging ----
// 8 waves, QBLK=128, KVBLK=64. LDS: K 2x16K + V 2x16K + P 16K = 80KB (2 blk/CU).
__global__ __launch_bounds__(512, 4) void attn_kernel(const u16* __restrict__ xqkv,
                                                      const u16* __restrict__ xk,
                                                      const u16* __restrict__ vt,
                                                      u16* __restrict__ attn_o) {
    __shared__ u16 Kl[2][64 * 128];   // [kv][hd], XOR-swizzled contents
    __shared__ u16 Vl[2][64 * 128];   // [hd][kv] (128 rows x 64), XOR-swizzled
    __shared__ u16 Pl[128 * 64];      // [q][kv], XOR-swizzled, wave-private rows
    int tid = threadIdx.x;
    int qt = blockIdx.x, h = blockIdx.y, b = blockIdx.z;
    int g = h >> 2;
    int q0 = qt * 128;
    int w = tid >> 6, lane = tid & 63, lg = lane >> 4, ln = lane & 15;

    const u16* kbase = xk + (size_t)(b * KVH_ + g) * S_ * HD_;
    const u16* vbase = vt + (size_t)(b * KVH_ + g) * HD_ * S_;

    // stage K/V tile tt into LDS buffer `buf` (linear dest + pre-swizzled src)
    auto stageKV = [&](int tt, int buf) {
        int kv0 = tt * 64;
#pragma unroll
        for (int i = 0; i < 2; i++) {  // K: 64 rows x 256B
            int flat = i * 512 + tid;
            int row = flat >> 4, cb = (flat & 15) * 16;
            gload_lds16(kbase + (kv0 + row) * HD_ + ((cb ^ ((row & 7) << 4)) >> 1),
                        &Kl[buf][flat * 8]);
        }
#pragma unroll
        for (int i = 0; i < 2; i++) {  // V: 128 rows x 128B
            int flat = i * 512 + tid;
            int row = flat >> 3, cb = (flat & 7) * 16;
            gload_lds16(vbase + (size_t)row * S_ + kv0 + ((cb ^ ((row & 7) << 4)) >> 1),
                        &Vl[buf][flat * 8]);
        }
    };

    // Q fragment: lane holds Q[q = q0+w*16+ln][d = kk*32+lg*8+j] (mfma B-operand)
    bf16x8 qf[4];
    {
        const u16* qp = xqkv + (size_t)(b * S_ + q0 + w * 16 + ln) * NQKV + h * HD_;
#pragma unroll
        for (int kk = 0; kk < 4; kk++) qf[kk] = *(const bf16x8*)(qp + kk * 32 + lg * 8);
    }

    f32x4 o[8];
#pragma unroll
    for (int i = 0; i < 8; i++) o[i] = zero4();
    float m_run = -1e30f, l_run = 0.0f;   // per-lane (q = ln), log2 domain

    const float SCL = 0.08838834764831845f * 1.4426950408889634f;  // 1/sqrt(128)*log2(e)

    int qrow = w * 16 + ln;
    char* pbase = (char*)Pl + qrow * 128;
    int sw = (ln & 7) << 4;

    stageKV(0, 0);
    __syncthreads();

    for (int t = 0; t < S_ / 64; t++) {
        int cur = t & 1;
        if (t < S_ / 64 - 1) stageKV(t + 1, cur ^ 1);  // async: lands by trailing barrier

        // QK^T swapped: sc[nf] holds S^T[kv = nf*16+lg*4+r][q = ln]
        f32x4 sc[4];
#pragma unroll
        for (int nf = 0; nf < 4; nf++) sc[nf] = zero4();
        __builtin_amdgcn_s_setprio(1);
#pragma unroll
        for (int nf = 0; nf < 4; nf++)
#pragma unroll
            for (int kk = 0; kk < 4; kk++) {
                int row = nf * 16 + ln;
                int cb = (kk * 64 + lg * 16) ^ ((row & 7) << 4);
                bf16x8 kf = *(const bf16x8*)((const char*)Kl[cur] + row * 256 + cb);
                sc[nf] = __builtin_amdgcn_mfma_f32_16x16x32_bf16(kf, qf[kk], sc[nf], 0, 0, 0);
            }
        __builtin_amdgcn_s_setprio(0);
#pragma unroll
        for (int nf = 0; nf < 4; nf++) sc[nf] *= SCL;  // log2 domain

        // per-lane softmax over kv (16 local values + cross-lg reduce)
        float v = sc[0][0];
#pragma unroll
        for (int nf = 0; nf < 4; nf++)
#pragma unroll
            for (int r = 0; r < 4; r++) v = fmaxf(v, sc[nf][r]);
        v = fmaxf(v, __shfl_xor(v, 16));
        v = fmaxf(v, __shfl_xor(v, 32));

        float corr = 1.0f;
        bool skip = (__all(v <= m_run + 8.0f) != 0);   // defer-max (T13)
        if (!skip) {
            float mnew = fmaxf(m_run, v);
            corr = EXP2(m_run - mnew);
            m_run = mnew;
            float c0 = __shfl(corr, lg * 4 + 0);
            float c1 = __shfl(corr, lg * 4 + 1);
            float c2 = __shfl(corr, lg * 4 + 2);
            float c3 = __shfl(corr, lg * 4 + 3);
#pragma unroll
            for (int i = 0; i < 8; i++) {
                f32x4 t4 = o[i];
                t4[0] *= c0; t4[1] *= c1; t4[2] *= c2; t4[3] *= c3;
                o[i] = t4;
            }
        }

        // P = exp2(S - m), packed bf16 pairs into swizzled wave-private Pl rows
        float lsum = 0.0f;
#pragma unroll
        for (int nf = 0; nf < 4; nf++) {
            float p0 = EXP2(sc[nf][0] - m_run);
            float p1 = EXP2(sc[nf][1] - m_run);
            float p2 = EXP2(sc[nf][2] - m_run);
            float p3 = EXP2(sc[nf][3] - m_run);
            lsum += (p0 + p1) + (p2 + p3);
            *(u32a*)(pbase + ((nf * 32 + lg * 8) ^ sw))     = cvt_pk_bf16(p0, p1);
            *(u32a*)(pbase + ((nf * 32 + lg * 8 + 4) ^ sw)) = cvt_pk_bf16(p2, p3);
        }
        lsum += __shfl_xor(lsum, 16);
        lsum += __shfl_xor(lsum, 32);
        l_run = l_run * corr + lsum;

        // P A-fragment: lane holds P[q=ln][kv = kk*32+lg*8+j]
        bf16x8 pf[2];
#pragma unroll
        for (int kk = 0; kk < 2; kk++)
            pf[kk] = *(const bf16x8*)(pbase + ((kk * 64 + lg * 16) ^ sw));

        // PV: o[nf] covers d = nf*16+ln, q rows = lg*4+r
        __builtin_amdgcn_s_setprio(1);
#pragma unroll
        for (int nf = 0; nf < 8; nf++)
#pragma unroll
            for (int kk = 0; kk < 2; kk++) {
                int row = nf * 16 + ln;
                int cb = (kk * 64 + lg * 16) ^ ((row & 7) << 4);
                bf16x8 vf = *(const bf16x8*)((const char*)Vl[cur] + row * 128 + cb);
                o[nf] = __builtin_amdgcn_mfma_f32_16x16x32_bf16(pf[kk], vf, o[nf], 0, 0, 0);
            }
        __builtin_amdgcn_s_setprio(0);

        if (t < S_ / 64 - 1) __syncthreads();  // drains t+1 stages (overlapped w/ compute)
    }

    // normalize + store bf16: q = q0 + w*16 + lg*4 + r, d = nf*16 + ln
    float i0 = 1.0f / __shfl(l_run, lg * 4 + 0);
    float i1 = 1.0f / __shfl(l_run, lg * 4 + 1);
    float i2 = 1.0f / __shfl(l_run, lg * 4 + 2);
    float i3 = 1.0f / __shfl(l_run, lg * 4 + 3);
#pragma unroll
    for (int nf = 0; nf < 8; nf++) {
        int rowb = (b * S_ + q0 + w * 16 + lg * 4) * (H_ * HD_) + h * HD_ + nf * 16 + ln;
        attn_o[rowb]                 = f2bf(o[nf][0] * i0);
        attn_o[rowb + 1 * H_ * HD_]  = f2bf(o[nf][1] * i1);
        attn_o[rowb + 2 * H_ * HD_]  = f2bf(o[nf][2] * i2);
        attn_o[rowb + 3 * H_ * HD_]  = f2bf(o[nf][3] * i3);
    }
}

extern "C" void kernel_launch(void* const* d_in, const int* in_sizes, int n_in,
                              void* d_out, int out_size, void* d_ws, size_t ws_size,
                              hipStream_t stream) {
    const float* x    = (const float*)d_in[0];
    // d_in[1] = start_pos (always 0 for this problem)
    const float* fcos = (const float*)d_in[2];
    const float* fsin = (const float*)d_in[3];
    const float* wq   = (const float*)d_in[4];
    const float* wk   = (const float*)d_in[5];
    const float* wv   = (const float*)d_in[6];
    const float* wo   = (const float*)d_in[7];
    float* out = (float*)d_out;

    char* ws = (char*)d_ws;
    // workspace layout (bytes)
    u16* x_b    = (u16*)(ws);                    // 16,777,216  (aliased by attn_o later)
    u16* wqkv_b = (u16*)(ws + 16777216);         // 12,582,912
    u16* wo_b   = (u16*)(ws + 29360128);         //  8,388,608
    u16* xqkv_b = (u16*)(ws + 37748736);         // 25,165,824
    u16* xk_b   = (u16*)(ws + 62914560);         //  4,194,304
    u16* vt_b   = (u16*)(ws + 67108864);         //  4,194,304
    u16* attn_o = x_b;                           // reuse: x_b dead after QKV GEMM

    // 1. convert inputs to bf16
    cvt_f32_bf16<<<4096, 256, 0, stream>>>(x, x_b, (NTOK * DIM_) / 4);
    cvt_f32_bf16<<<2048, 256, 0, stream>>>(wq, wqkv_b, (2048 * 2048) / 4);
    cvt_f32_bf16<<<512, 256, 0, stream>>>(wk, wqkv_b + 2048 * 2048, (512 * 2048) / 4);
    cvt_f32_bf16<<<512, 256, 0, stream>>>(wv, wqkv_b + 2560 * 2048, (512 * 2048) / 4);
    cvt_f32_bf16<<<2048, 256, 0, stream>>>(wo, wo_b, (2048 * 2048) / 4);

    // 2. fused QKV GEMM + RoPE epilogue (Q rope'd in xqkv, K rope'd to xk, V to xqkv)
    gemm_nt<1><<<dim3(NQKV / 128, NTOK / 128), 256, 0, stream>>>(
        x_b, wqkv_b, xqkv_b, xk_b, fcos, fsin, NTOK, NQKV, DIM_);

    // 3. V transpose -> (b,g,d,pos)
    vtrans<<<1024, 256, 0, stream>>>(xqkv_b, vt_b);

    // 4. attention: QBLK=128, 512 threads, 2 blocks/CU
    attn_kernel<<<dim3(S_ / 128, H_, B_), 512, 0, stream>>>(xqkv_b, xk_b, vt_b, attn_o);

    // 5. output projection: (4096 x 2048 x 2048), fp32 out
    gemm_nt<0><<<dim3(DIM_ / 128, NTOK / 128), 256, 0, stream>>>(
        attn_o, wo_b, out, nullptr, nullptr, nullptr, NTOK, DIM_, DIM_);
}

// Round 7
// 402.759 us; speedup vs baseline: 1.0545x; 1.0545x over previous
//
#include <hip/hip_runtime.h>
#include <stdint.h>

// ---- problem constants ----
#define B_    2
#define S_    2048
#define DIM_  2048
#define H_    16
#define KVH_  4
#define HD_   128
#define NTOK  (B_*S_)   // 4096
#define NQKV  3072      // H*HD + 2*KVH*HD

typedef unsigned short u16;
typedef unsigned int u32a __attribute__((may_alias));
typedef short bf16x8 __attribute__((ext_vector_type(8), may_alias));
typedef float f32x4 __attribute__((ext_vector_type(4), may_alias));
typedef unsigned short u16x8 __attribute__((ext_vector_type(8), may_alias));
typedef unsigned short u16x4 __attribute__((ext_vector_type(4), may_alias));

__device__ __forceinline__ float bf2f(u16 v) {
    unsigned u = (unsigned)v << 16;
    return __builtin_bit_cast(float, u);
}
__device__ __forceinline__ u16 f2bf(float f) {
    unsigned u = __builtin_bit_cast(unsigned, f);
    unsigned r = (u + 0x7fffu + ((u >> 16) & 1u)) >> 16;  // RNE
    return (u16)r;
}
__device__ __forceinline__ unsigned cvt_pk_bf16(float lo, float hi) {
    unsigned r;
    asm("v_cvt_pk_bf16_f32 %0, %1, %2" : "=v"(r) : "v"(lo), "v"(hi));
    return r;
}

#if __has_builtin(__builtin_amdgcn_exp2f)
#define EXP2(x) __builtin_amdgcn_exp2f(x)
#else
#define EXP2(x) exp2f(x)
#endif

__device__ __forceinline__ void gload_lds16(const void* g, void* l) {
    __builtin_amdgcn_global_load_lds(
        (const __attribute__((address_space(1))) void*)g,
        (__attribute__((address_space(3))) void*)l, 16, 0, 0);
}

__device__ __forceinline__ f32x4 zero4() { f32x4 z = {0.f, 0.f, 0.f, 0.f}; return z; }

// ---- fp32 -> bf16 convert (vectorized) ----
__global__ void cvt_f32_bf16(const float* __restrict__ src, u16* __restrict__ dst, int n4) {
    int i = blockIdx.x * blockDim.x + threadIdx.x;
    int stride = gridDim.x * blockDim.x;
    for (; i < n4; i += stride) {
        float4 v = ((const float4*)src)[i];
        u16x4 o;
        o[0] = f2bf(v.x); o[1] = f2bf(v.y); o[2] = f2bf(v.z); o[3] = f2bf(v.w);
        ((u16x4*)dst)[i] = o;
    }
}

// ---- bf16 NT GEMM: C[M][N] = A[M][K] * Bt[N][K]^T ----
// 128x128 tile, BK=64, 4 waves (2x2), m97-style 2-barrier K-loop.
// 1-D grid with bijective XCD swizzle (T1): nwg must be divisible by 8.
template <int WRITE_BF16>
__global__ __launch_bounds__(256) void gemm_nt(const u16* __restrict__ A,
                                               const u16* __restrict__ Bt,
                                               void* __restrict__ C,
                                               int M, int N, int K, int nbx) {
    __shared__ u16 As[128 * 64];
    __shared__ u16 Bs[128 * 64];
    int tid = threadIdx.x;
    int nwg = gridDim.x;
    int bid = blockIdx.x;
    int swz = (bid & 7) * (nwg >> 3) + (bid >> 3);   // XCD-contiguous chunks
    int m0 = (swz / nbx) * 128, n0 = (swz % nbx) * 128;
    int lane = tid & 63, lg = lane >> 4, ln = lane & 15;
    int w = tid >> 6, wr = w >> 1, wc = w & 1;

    f32x4 acc[4][4];
#pragma unroll
    for (int i = 0; i < 4; i++)
#pragma unroll
        for (int j = 0; j < 4; j++) acc[i][j] = zero4();

    int nk = K >> 6;
    for (int kt = 0; kt < nk; kt++) {
        int k0 = kt << 6;
#pragma unroll
        for (int i = 0; i < 4; i++) {  // A tile: 128 rows x 64 cols bf16
            int flat = i * 256 + tid;
            int row = flat >> 3, c16 = flat & 7;
            gload_lds16(A + (m0 + row) * K + k0 + c16 * 8, &As[flat * 8]);
        }
#pragma unroll
        for (int i = 0; i < 4; i++) {  // B tile
            int flat = i * 256 + tid;
            int row = flat >> 3, c16 = flat & 7;
            gload_lds16(Bt + (n0 + row) * K + k0 + c16 * 8, &Bs[flat * 8]);
        }
        __syncthreads();  // drains vmcnt before reads

        bf16x8 af[4][2], bfr[4][2];
#pragma unroll
        for (int mf = 0; mf < 4; mf++)
#pragma unroll
            for (int kk = 0; kk < 2; kk++)
                af[mf][kk] = *(const bf16x8*)&As[(wr * 64 + mf * 16 + ln) * 64 + kk * 32 + lg * 8];
#pragma unroll
        for (int nf = 0; nf < 4; nf++)
#pragma unroll
            for (int kk = 0; kk < 2; kk++)
                bfr[nf][kk] = *(const bf16x8*)&Bs[(wc * 64 + nf * 16 + ln) * 64 + kk * 32 + lg * 8];
#pragma unroll
        for (int kk = 0; kk < 2; kk++)
#pragma unroll
            for (int mf = 0; mf < 4; mf++)
#pragma unroll
                for (int nf = 0; nf < 4; nf++)
                    acc[mf][nf] = __builtin_amdgcn_mfma_f32_16x16x32_bf16(
                        af[mf][kk], bfr[nf][kk], acc[mf][nf], 0, 0, 0);
        __syncthreads();  // before next overwrite
    }

    // epilogue: C layout row=(lane>>4)*4+reg, col=lane&15 per 16x16 fragment
#pragma unroll
    for (int mf = 0; mf < 4; mf++)
#pragma unroll
        for (int nf = 0; nf < 4; nf++)
#pragma unroll
            for (int r = 0; r < 4; r++) {
                int row = m0 + wr * 64 + mf * 16 + lg * 4 + r;
                int col = n0 + wc * 64 + nf * 16 + ln;
                float v = acc[mf][nf][r];
                if (WRITE_BF16)
                    ((u16*)C)[row * N + col] = f2bf(v);
                else
                    ((float*)C)[row * N + col] = v;
            }
}

// ---- RoPE: in-place on Q columns of xqkv (stride 3072); K -> xk (b,g,s,d) ----
__global__ void rope_k(u16* __restrict__ xqkv, u16* __restrict__ xk,
                       const float* __restrict__ fcos, const float* __restrict__ fsin) {
    int tok = blockIdx.x;
    int b = tok >> 11, pos = tok & 2047;
    int tid = threadIdx.x;
#pragma unroll
    for (int it = 0; it < 5; it++) {  // 1280 pairs = 5*256
        int p = it * 256 + tid;
        int j = p & 63;
        float c = fcos[pos * 64 + j], s = fsin[pos * 64 + j];
        int base = tok * NQKV + 2 * p;
        float x0 = bf2f(xqkv[base]), x1 = bf2f(xqkv[base + 1]);
        float o0 = x0 * c - x1 * s;
        float o1 = x0 * s + x1 * c;
        if (p < 1024) {  // Q: 16 heads * 64 pairs, in place
            xqkv[base] = f2bf(o0);
            xqkv[base + 1] = f2bf(o1);
        } else {  // K: 4 heads * 64 pairs -> (b,g,pos,d)
            int kp = p - 1024;
            int gg = kp >> 6;
            int kb = ((b * KVH_ + gg) * S_ + pos) * HD_ + 2 * j;
            xk[kb] = f2bf(o0);
            xk[kb + 1] = f2bf(o1);
        }
    }
}

// ---- V transpose: xqkv V cols -> vt (b,g,d,pos) bf16 ----
__global__ void vtrans(const u16* __restrict__ xqkv, u16* __restrict__ vt) {
    int tid = threadIdx.x;
    int blk = blockIdx.x;           // bg * 128 + ptile
    int ptile = blk & 127;          // S/16 = 128
    int bg = blk >> 7;              // 0..7
    int b = bg >> 2, gg = bg & 3;
    int d = tid & 127, pg = tid >> 7;
    int pos0 = ptile * 16 + pg * 8;
    u16x8 v;
#pragma unroll
    for (int i = 0; i < 8; i++)
        v[i] = xqkv[(b * S_ + pos0 + i) * NQKV + 2560 + gg * HD_ + d];  // coalesced over d
    *(u16x8*)(vt + (bg * HD_ + d) * S_ + pos0) = v;
}

// ---- flash attention v3: swapped QK^T, async double-buffered K/V staging ----
// 8 waves, QBLK=128, KVBLK=64. LDS: K 2x16K + V 2x16K + P 16K = 80KB (2 blk/CU).
__global__ __launch_bounds__(512, 4) void attn_kernel(const u16* __restrict__ xqkv,
                                                      const u16* __restrict__ xk,
                                                      const u16* __restrict__ vt,
                                                      u16* __restrict__ attn_o) {
    __shared__ u16 Kl[2][64 * 128];   // [kv][hd], XOR-swizzled contents
    __shared__ u16 Vl[2][64 * 128];   // [hd][kv] (128 rows x 64), XOR-swizzled
    __shared__ u16 Pl[128 * 64];      // [q][kv], XOR-swizzled, wave-private rows
    int tid = threadIdx.x;
    int qt = blockIdx.x, h = blockIdx.y, b = blockIdx.z;
    int g = h >> 2;
    int q0 = qt * 128;
    int w = tid >> 6, lane = tid & 63, lg = lane >> 4, ln = lane & 15;

    const u16* kbase = xk + (size_t)(b * KVH_ + g) * S_ * HD_;
    const u16* vbase = vt + (size_t)(b * KVH_ + g) * HD_ * S_;

    // stage K/V tile tt into LDS buffer `buf` (linear dest + pre-swizzled src)
    auto stageKV = [&](int tt, int buf) {
        int kv0 = tt * 64;
#pragma unroll
        for (int i = 0; i < 2; i++) {  // K: 64 rows x 256B
            int flat = i * 512 + tid;
            int row = flat >> 4, cb = (flat & 15) * 16;
            gload_lds16(kbase + (kv0 + row) * HD_ + ((cb ^ ((row & 7) << 4)) >> 1),
                        &Kl[buf][flat * 8]);
        }
#pragma unroll
        for (int i = 0; i < 2; i++) {  // V: 128 rows x 128B
            int flat = i * 512 + tid;
            int row = flat >> 3, cb = (flat & 7) * 16;
            gload_lds16(vbase + (size_t)row * S_ + kv0 + ((cb ^ ((row & 7) << 4)) >> 1),
                        &Vl[buf][flat * 8]);
        }
    };

    // Q fragment: lane holds Q[q = q0+w*16+ln][d = kk*32+lg*8+j] (mfma B-operand)
    bf16x8 qf[4];
    {
        const u16* qp = xqkv + (size_t)(b * S_ + q0 + w * 16 + ln) * NQKV + h * HD_;
#pragma unroll
        for (int kk = 0; kk < 4; kk++) qf[kk] = *(const bf16x8*)(qp + kk * 32 + lg * 8);
    }

    f32x4 o[8];
#pragma unroll
    for (int i = 0; i < 8; i++) o[i] = zero4();
    float m_run = -1e30f, l_run = 0.0f;   // per-lane (q = ln), log2 domain

    const float SCL = 0.08838834764831845f * 1.4426950408889634f;  // 1/sqrt(128)*log2(e)

    int qrow = w * 16 + ln;
    char* pbase = (char*)Pl + qrow * 128;
    int sw = (ln & 7) << 4;

    stageKV(0, 0);
    __syncthreads();

    for (int t = 0; t < S_ / 64; t++) {
        int cur = t & 1;
        if (t < S_ / 64 - 1) stageKV(t + 1, cur ^ 1);  // async: lands by trailing barrier

        // QK^T swapped: sc[nf] holds S^T[kv = nf*16+lg*4+r][q = ln]
        f32x4 sc[4];
#pragma unroll
        for (int nf = 0; nf < 4; nf++) sc[nf] = zero4();
        __builtin_amdgcn_s_setprio(1);
#pragma unroll
        for (int nf = 0; nf < 4; nf++)
#pragma unroll
            for (int kk = 0; kk < 4; kk++) {
                int row = nf * 16 + ln;
                int cb = (kk * 64 + lg * 16) ^ ((row & 7) << 4);
                bf16x8 kf = *(const bf16x8*)((const char*)Kl[cur] + row * 256 + cb);
                sc[nf] = __builtin_amdgcn_mfma_f32_16x16x32_bf16(kf, qf[kk], sc[nf], 0, 0, 0);
            }
        __builtin_amdgcn_s_setprio(0);
#pragma unroll
        for (int nf = 0; nf < 4; nf++) sc[nf] *= SCL;  // log2 domain

        // per-lane softmax over kv (16 local values + cross-lg reduce)
        float v = sc[0][0];
#pragma unroll
        for (int nf = 0; nf < 4; nf++)
#pragma unroll
            for (int r = 0; r < 4; r++) v = fmaxf(v, sc[nf][r]);
        v = fmaxf(v, __shfl_xor(v, 16));
        v = fmaxf(v, __shfl_xor(v, 32));

        float corr = 1.0f;
        bool skip = (__all(v <= m_run + 8.0f) != 0);   // defer-max (T13)
        if (!skip) {
            float mnew = fmaxf(m_run, v);
            corr = EXP2(m_run - mnew);
            m_run = mnew;
            float c0 = __shfl(corr, lg * 4 + 0);
            float c1 = __shfl(corr, lg * 4 + 1);
            float c2 = __shfl(corr, lg * 4 + 2);
            float c3 = __shfl(corr, lg * 4 + 3);
#pragma unroll
            for (int i = 0; i < 8; i++) {
                f32x4 t4 = o[i];
                t4[0] *= c0; t4[1] *= c1; t4[2] *= c2; t4[3] *= c3;
                o[i] = t4;
            }
        }

        // P = exp2(S - m), packed bf16 pairs into swizzled wave-private Pl rows
        float lsum = 0.0f;
#pragma unroll
        for (int nf = 0; nf < 4; nf++) {
            float p0 = EXP2(sc[nf][0] - m_run);
            float p1 = EXP2(sc[nf][1] - m_run);
            float p2 = EXP2(sc[nf][2] - m_run);
            float p3 = EXP2(sc[nf][3] - m_run);
            lsum += (p0 + p1) + (p2 + p3);
            *(u32a*)(pbase + ((nf * 32 + lg * 8) ^ sw))     = cvt_pk_bf16(p0, p1);
            *(u32a*)(pbase + ((nf * 32 + lg * 8 + 4) ^ sw)) = cvt_pk_bf16(p2, p3);
        }
        lsum += __shfl_xor(lsum, 16);
        lsum += __shfl_xor(lsum, 32);
        l_run = l_run * corr + lsum;

        // P A-fragment: lane holds P[q=ln][kv = kk*32+lg*8+j]
        bf16x8 pf[2];
#pragma unroll
        for (int kk = 0; kk < 2; kk++)
            pf[kk] = *(const bf16x8*)(pbase + ((kk * 64 + lg * 16) ^ sw));

        // PV: o[nf] covers d = nf*16+ln, q rows = lg*4+r
        __builtin_amdgcn_s_setprio(1);
#pragma unroll
        for (int nf = 0; nf < 8; nf++)
#pragma unroll
            for (int kk = 0; kk < 2; kk++) {
                int row = nf * 16 + ln;
                int cb = (kk * 64 + lg * 16) ^ ((row & 7) << 4);
                bf16x8 vf = *(const bf16x8*)((const char*)Vl[cur] + row * 128 + cb);
                o[nf] = __builtin_amdgcn_mfma_f32_16x16x32_bf16(pf[kk], vf, o[nf], 0, 0, 0);
            }
        __builtin_amdgcn_s_setprio(0);

        if (t < S_ / 64 - 1) __syncthreads();  // drains t+1 stages (overlapped w/ compute)
    }

    // normalize + store bf16: q = q0 + w*16 + lg*4 + r, d = nf*16 + ln
    float i0 = 1.0f / __shfl(l_run, lg * 4 + 0);
    float i1 = 1.0f / __shfl(l_run, lg * 4 + 1);
    float i2 = 1.0f / __shfl(l_run, lg * 4 + 2);
    float i3 = 1.0f / __shfl(l_run, lg * 4 + 3);
#pragma unroll
    for (int nf = 0; nf < 8; nf++) {
        int rowb = (b * S_ + q0 + w * 16 + lg * 4) * (H_ * HD_) + h * HD_ + nf * 16 + ln;
        attn_o[rowb]                 = f2bf(o[nf][0] * i0);
        attn_o[rowb + 1 * H_ * HD_]  = f2bf(o[nf][1] * i1);
        attn_o[rowb + 2 * H_ * HD_]  = f2bf(o[nf][2] * i2);
        attn_o[rowb + 3 * H_ * HD_]  = f2bf(o[nf][3] * i3);
    }
}

extern "C" void kernel_launch(void* const* d_in, const int* in_sizes, int n_in,
                              void* d_out, int out_size, void* d_ws, size_t ws_size,
                              hipStream_t stream) {
    const float* x    = (const float*)d_in[0];
    // d_in[1] = start_pos (always 0 for this problem)
    const float* fcos = (const float*)d_in[2];
    const float* fsin = (const float*)d_in[3];
    const float* wq   = (const float*)d_in[4];
    const float* wk   = (const float*)d_in[5];
    const float* wv   = (const float*)d_in[6];
    const float* wo   = (const float*)d_in[7];
    float* out = (float*)d_out;

    char* ws = (char*)d_ws;
    // workspace layout (bytes)
    u16* x_b    = (u16*)(ws);                    // 16,777,216  (aliased by attn_o later)
    u16* wqkv_b = (u16*)(ws + 16777216);         // 12,582,912
    u16* wo_b   = (u16*)(ws + 29360128);         //  8,388,608
    u16* xqkv_b = (u16*)(ws + 37748736);         // 25,165,824
    u16* xk_b   = (u16*)(ws + 62914560);         //  4,194,304
    u16* vt_b   = (u16*)(ws + 67108864);         //  4,194,304
    u16* attn_o = x_b;                           // reuse: x_b dead after QKV GEMM

    // 1. convert inputs to bf16
    cvt_f32_bf16<<<4096, 256, 0, stream>>>(x, x_b, (NTOK * DIM_) / 4);
    cvt_f32_bf16<<<2048, 256, 0, stream>>>(wq, wqkv_b, (2048 * 2048) / 4);
    cvt_f32_bf16<<<512, 256, 0, stream>>>(wk, wqkv_b + 2048 * 2048, (512 * 2048) / 4);
    cvt_f32_bf16<<<512, 256, 0, stream>>>(wv, wqkv_b + 2560 * 2048, (512 * 2048) / 4);
    cvt_f32_bf16<<<2048, 256, 0, stream>>>(wo, wo_b, (2048 * 2048) / 4);

    // 2. fused QKV GEMM: (4096 x 3072 x 2048), bf16 out, XCD-swizzled 1-D grid
    gemm_nt<1><<<(NQKV / 128) * (NTOK / 128), 256, 0, stream>>>(
        x_b, wqkv_b, xqkv_b, NTOK, NQKV, DIM_, NQKV / 128);

    // 3. RoPE (Q in place, K -> xk_b)
    rope_k<<<NTOK, 256, 0, stream>>>(xqkv_b, xk_b, fcos, fsin);

    // 4. V transpose -> (b,g,d,pos)
    vtrans<<<1024, 256, 0, stream>>>(xqkv_b, vt_b);

    // 5. attention: QBLK=128, 512 threads, 2 blocks/CU
    attn_kernel<<<dim3(S_ / 128, H_, B_), 512, 0, stream>>>(xqkv_b, xk_b, vt_b, attn_o);

    // 6. output projection: (4096 x 2048 x 2048), fp32 out, XCD-swizzled 1-D grid
    gemm_nt<0><<<(DIM_ / 128) * (NTOK / 128), 256, 0, stream>>>(
        attn_o, wo_b, out, NTOK, DIM_, DIM_, DIM_ / 128);
}

// Round 8
// 382.262 us; speedup vs baseline: 1.1110x; 1.0536x over previous
//
#include <hip/hip_runtime.h>
#include <stdint.h>

// ---- problem constants ----
#define B_    2
#define S_    2048
#define DIM_  2048
#define H_    16
#define KVH_  4
#define HD_   128
#define NTOK  (B_*S_)   // 4096
#define NQKV  3072      // H*HD + 2*KVH*HD

typedef unsigned short u16;
typedef unsigned int u32a __attribute__((may_alias));
typedef short bf16x8 __attribute__((ext_vector_type(8), may_alias));
typedef float f32x4 __attribute__((ext_vector_type(4), may_alias));
typedef unsigned short u16x8 __attribute__((ext_vector_type(8), may_alias));
typedef unsigned short u16x4 __attribute__((ext_vector_type(4), may_alias));

__device__ __forceinline__ float bf2f(u16 v) {
    unsigned u = (unsigned)v << 16;
    return __builtin_bit_cast(float, u);
}
__device__ __forceinline__ u16 f2bf(float f) {
    unsigned u = __builtin_bit_cast(unsigned, f);
    unsigned r = (u + 0x7fffu + ((u >> 16) & 1u)) >> 16;  // RNE
    return (u16)r;
}
__device__ __forceinline__ unsigned cvt_pk_bf16(float lo, float hi) {
    unsigned r;
    asm("v_cvt_pk_bf16_f32 %0, %1, %2" : "=v"(r) : "v"(lo), "v"(hi));
    return r;
}

#if __has_builtin(__builtin_amdgcn_exp2f)
#define EXP2(x) __builtin_amdgcn_exp2f(x)
#else
#define EXP2(x) exp2f(x)
#endif

__device__ __forceinline__ void gload_lds16(const void* g, void* l) {
    __builtin_amdgcn_global_load_lds(
        (const __attribute__((address_space(1))) void*)g,
        (__attribute__((address_space(3))) void*)l, 16, 0, 0);
}

__device__ __forceinline__ f32x4 zero4() { f32x4 z = {0.f, 0.f, 0.f, 0.f}; return z; }

// ---- fp32 -> bf16 convert (vectorized) ----
__global__ void cvt_f32_bf16(const float* __restrict__ src, u16* __restrict__ dst, int n4) {
    int i = blockIdx.x * blockDim.x + threadIdx.x;
    int stride = gridDim.x * blockDim.x;
    for (; i < n4; i += stride) {
        float4 v = ((const float4*)src)[i];
        u16x4 o;
        o[0] = f2bf(v.x); o[1] = f2bf(v.y); o[2] = f2bf(v.z); o[3] = f2bf(v.w);
        ((u16x4*)dst)[i] = o;
    }
}

// ---- 256x256 8-phase bf16 NT GEMM (T2+T3+T4+T5) ----
// C[M][N] = A[M][K] * Bt[N][K]^T. BK=64 staged as 2 K-halves of 32.
// 8 waves (2M x 4N), per-wave output 128x64. LDS 128KB: [dbuf][kk][A,B] 16KB each.
// Stage stream: half-tile u (A/B of K-half) staged at phase u-6; counted vmcnt(4)
// once per K-tile at sub3 (before the end barrier -> cross-wave landing publish).
template <int WRITE_BF16>
__global__ __launch_bounds__(512, 2) void gemm256(const u16* __restrict__ A,
                                                  const u16* __restrict__ Bt,
                                                  void* __restrict__ C,
                                                  int M, int N, int K, int nbx) {
    __shared__ u16 AB[8][256 * 32];   // [dbuf*4 + kk*2 + ab][256 rows x 32 k] = 128KB
    const int tid = threadIdx.x;
    const int nwg = gridDim.x;
    int bid = blockIdx.x;
    int swz = (bid & 7) * (nwg >> 3) + (bid >> 3);   // XCD-contiguous chunks
    const int m0 = (swz / nbx) * 256, n0 = (swz % nbx) * 256;
    const int lane = tid & 63, lg = (lane >> 4) & 3, ln = lane & 15;
    const int w = tid >> 6, wr = w >> 2, wc = w & 3;  // 2M x 4N waves
    const int nk2 = K >> 6;
    const int aswl = (lg ^ (ln & 3)) << 4;            // read-side XOR slot (row&3 == ln&3)

    f32x4 acc[8][4];
#pragma unroll
    for (int i = 0; i < 8; i++)
#pragma unroll
        for (int j = 0; j < 4; j++) acc[i][j] = zero4();

    // stage half-tile u: ab = u&1 (0=A,1=B), K-half kap = u>>1 (kt = kap>>1, kk = kap&1)
    auto stage = [&](int u) {
        int ab = u & 1, kap = u >> 1;
        int skk = kap & 1, skt = kap >> 1, sdb = skt & 1;
        u16* base = AB[sdb * 4 + skk * 2 + ab];
        const u16* src = ab ? (Bt + (size_t)n0 * K) : (A + (size_t)m0 * K);
        int kcol = skt * 64 + skk * 32;
#pragma unroll
        for (int i = 0; i < 2; i++) {
            int flat = i * 512 + tid;
            int row = flat >> 2, c8 = flat & 3;          // 256 rows x 4 slots of 8 bf16
            gload_lds16(src + (size_t)row * K + kcol + ((c8 ^ (row & 3)) * 8),
                        base + flat * 8);                 // linear LDS dest (HW pattern)
        }
    };

    // prologue: 6 half-tiles in flight, wait K-tile 0 landed, publish via barrier
    for (int u = 0; u < 6; u++) stage(u);
    asm volatile("s_waitcnt vmcnt(4)" ::: "memory");
    __builtin_amdgcn_s_barrier();

    for (int kt = 0; kt < nk2; kt++) {
        const int dbuf = kt & 1;
        bf16x8 bfr[4];
#pragma unroll
        for (int sub = 0; sub < 4; sub++) {
            const int kk = sub >> 1, g = sub & 1;
            const char* Abuf = (const char*)AB[dbuf * 4 + kk * 2 + 0];
            const char* Bbuf = (const char*)AB[dbuf * 4 + kk * 2 + 1];
            bf16x8 af[4];
            if (g == 0) {
#pragma unroll
                for (int nf = 0; nf < 4; nf++)
                    bfr[nf] = *(const bf16x8*)(Bbuf + (wc * 64 + nf * 16 + ln) * 64 + aswl);
            }
#pragma unroll
            for (int mf2 = 0; mf2 < 4; mf2++)
                af[mf2] = *(const bf16x8*)(Abuf + (wr * 128 + (g * 4 + mf2) * 16 + ln) * 64 + aswl);

            int u = kt * 4 + sub + 6;
            if (u < nk2 * 4) stage(u);

            __builtin_amdgcn_s_barrier();
            asm volatile("s_waitcnt lgkmcnt(0)" ::: "memory");
            __builtin_amdgcn_sched_barrier(0);
            __builtin_amdgcn_s_setprio(1);
#pragma unroll
            for (int mf2 = 0; mf2 < 4; mf2++)
#pragma unroll
                for (int nf = 0; nf < 4; nf++)
                    acc[g * 4 + mf2][nf] = __builtin_amdgcn_mfma_f32_16x16x32_bf16(
                        af[mf2], bfr[nf], acc[g * 4 + mf2][nf], 0, 0, 0);
            __builtin_amdgcn_s_setprio(0);
            if (sub == 3) {   // counted vmcnt for NEXT tile, before end barrier
                if (kt == nk2 - 2) { asm volatile("s_waitcnt vmcnt(0)" ::: "memory"); }
                else if (kt < nk2 - 2) { asm volatile("s_waitcnt vmcnt(4)" ::: "memory"); }
            }
            __builtin_amdgcn_s_barrier();
        }
    }

    // epilogue: row = m0 + wr*128 + mf*16 + lg*4 + r, col = n0 + wc*64 + nf*16 + ln
#pragma unroll
    for (int mf = 0; mf < 8; mf++)
#pragma unroll
        for (int nf = 0; nf < 4; nf++)
#pragma unroll
            for (int r = 0; r < 4; r++) {
                int row = m0 + wr * 128 + mf * 16 + lg * 4 + r;
                int col = n0 + wc * 64 + nf * 16 + ln;
                if (WRITE_BF16)
                    ((u16*)C)[(size_t)row * N + col] = f2bf(acc[mf][nf][r]);
                else
                    ((float*)C)[(size_t)row * N + col] = acc[mf][nf][r];
            }
}

// ---- RoPE: in-place on Q columns of xqkv (stride 3072); K -> xk (b,g,s,d) ----
__global__ void rope_k(u16* __restrict__ xqkv, u16* __restrict__ xk,
                       const float* __restrict__ fcos, const float* __restrict__ fsin) {
    int tok = blockIdx.x;
    int b = tok >> 11, pos = tok & 2047;
    int tid = threadIdx.x;
#pragma unroll
    for (int it = 0; it < 5; it++) {  // 1280 pairs = 5*256
        int p = it * 256 + tid;
        int j = p & 63;
        float c = fcos[pos * 64 + j], s = fsin[pos * 64 + j];
        int base = tok * NQKV + 2 * p;
        float x0 = bf2f(xqkv[base]), x1 = bf2f(xqkv[base + 1]);
        float o0 = x0 * c - x1 * s;
        float o1 = x0 * s + x1 * c;
        if (p < 1024) {  // Q: 16 heads * 64 pairs, in place
            xqkv[base] = f2bf(o0);
            xqkv[base + 1] = f2bf(o1);
        } else {  // K: 4 heads * 64 pairs -> (b,g,pos,d)
            int kp = p - 1024;
            int gg = kp >> 6;
            int kb = ((b * KVH_ + gg) * S_ + pos) * HD_ + 2 * j;
            xk[kb] = f2bf(o0);
            xk[kb + 1] = f2bf(o1);
        }
    }
}

// ---- V transpose: xqkv V cols -> vt (b,g,d,pos) bf16 ----
__global__ void vtrans(const u16* __restrict__ xqkv, u16* __restrict__ vt) {
    int tid = threadIdx.x;
    int blk = blockIdx.x;           // bg * 128 + ptile
    int ptile = blk & 127;          // S/16 = 128
    int bg = blk >> 7;              // 0..7
    int b = bg >> 2, gg = bg & 3;
    int d = tid & 127, pg = tid >> 7;
    int pos0 = ptile * 16 + pg * 8;
    u16x8 v;
#pragma unroll
    for (int i = 0; i < 8; i++)
        v[i] = xqkv[(b * S_ + pos0 + i) * NQKV + 2560 + gg * HD_ + d];  // coalesced over d
    *(u16x8*)(vt + (bg * HD_ + d) * S_ + pos0) = v;
}

// ---- flash attention v3: swapped QK^T, async double-buffered K/V staging ----
// 8 waves, QBLK=128, KVBLK=64. LDS: K 2x16K + V 2x16K + P 16K = 80KB (2 blk/CU).
__global__ __launch_bounds__(512, 4) void attn_kernel(const u16* __restrict__ xqkv,
                                                      const u16* __restrict__ xk,
                                                      const u16* __restrict__ vt,
                                                      u16* __restrict__ attn_o) {
    __shared__ u16 Kl[2][64 * 128];   // [kv][hd], XOR-swizzled contents
    __shared__ u16 Vl[2][64 * 128];   // [hd][kv] (128 rows x 64), XOR-swizzled
    __shared__ u16 Pl[128 * 64];      // [q][kv], XOR-swizzled, wave-private rows
    int tid = threadIdx.x;
    int qt = blockIdx.x, h = blockIdx.y, b = blockIdx.z;
    int g = h >> 2;
    int q0 = qt * 128;
    int w = tid >> 6, lane = tid & 63, lg = lane >> 4, ln = lane & 15;

    const u16* kbase = xk + (size_t)(b * KVH_ + g) * S_ * HD_;
    const u16* vbase = vt + (size_t)(b * KVH_ + g) * HD_ * S_;

    // stage K/V tile tt into LDS buffer `buf` (linear dest + pre-swizzled src)
    auto stageKV = [&](int tt, int buf) {
        int kv0 = tt * 64;
#pragma unroll
        for (int i = 0; i < 2; i++) {  // K: 64 rows x 256B
            int flat = i * 512 + tid;
            int row = flat >> 4, cb = (flat & 15) * 16;
            gload_lds16(kbase + (kv0 + row) * HD_ + ((cb ^ ((row & 7) << 4)) >> 1),
                        &Kl[buf][flat * 8]);
        }
#pragma unroll
        for (int i = 0; i < 2; i++) {  // V: 128 rows x 128B
            int flat = i * 512 + tid;
            int row = flat >> 3, cb = (flat & 7) * 16;
            gload_lds16(vbase + (size_t)row * S_ + kv0 + ((cb ^ ((row & 7) << 4)) >> 1),
                        &Vl[buf][flat * 8]);
        }
    };

    // Q fragment: lane holds Q[q = q0+w*16+ln][d = kk*32+lg*8+j] (mfma B-operand)
    bf16x8 qf[4];
    {
        const u16* qp = xqkv + (size_t)(b * S_ + q0 + w * 16 + ln) * NQKV + h * HD_;
#pragma unroll
        for (int kk = 0; kk < 4; kk++) qf[kk] = *(const bf16x8*)(qp + kk * 32 + lg * 8);
    }

    f32x4 o[8];
#pragma unroll
    for (int i = 0; i < 8; i++) o[i] = zero4();
    float m_run = -1e30f, l_run = 0.0f;   // per-lane (q = ln), log2 domain

    const float SCL = 0.08838834764831845f * 1.4426950408889634f;  // 1/sqrt(128)*log2(e)

    int qrow = w * 16 + ln;
    char* pbase = (char*)Pl + qrow * 128;
    int sw = (ln & 7) << 4;

    stageKV(0, 0);
    __syncthreads();

    for (int t = 0; t < S_ / 64; t++) {
        int cur = t & 1;
        if (t < S_ / 64 - 1) stageKV(t + 1, cur ^ 1);  // async: lands by trailing barrier

        // QK^T swapped: sc[nf] holds S^T[kv = nf*16+lg*4+r][q = ln]
        f32x4 sc[4];
#pragma unroll
        for (int nf = 0; nf < 4; nf++) sc[nf] = zero4();
        __builtin_amdgcn_s_setprio(1);
#pragma unroll
        for (int nf = 0; nf < 4; nf++)
#pragma unroll
            for (int kk = 0; kk < 4; kk++) {
                int row = nf * 16 + ln;
                int cb = (kk * 64 + lg * 16) ^ ((row & 7) << 4);
                bf16x8 kf = *(const bf16x8*)((const char*)Kl[cur] + row * 256 + cb);
                sc[nf] = __builtin_amdgcn_mfma_f32_16x16x32_bf16(kf, qf[kk], sc[nf], 0, 0, 0);
            }
        __builtin_amdgcn_s_setprio(0);
#pragma unroll
        for (int nf = 0; nf < 4; nf++) sc[nf] *= SCL;  // log2 domain

        // per-lane softmax over kv (16 local values + cross-lg reduce)
        float v = sc[0][0];
#pragma unroll
        for (int nf = 0; nf < 4; nf++)
#pragma unroll
            for (int r = 0; r < 4; r++) v = fmaxf(v, sc[nf][r]);
        v = fmaxf(v, __shfl_xor(v, 16));
        v = fmaxf(v, __shfl_xor(v, 32));

        float corr = 1.0f;
        bool skip = (__all(v <= m_run + 8.0f) != 0);   // defer-max (T13)
        if (!skip) {
            float mnew = fmaxf(m_run, v);
            corr = EXP2(m_run - mnew);
            m_run = mnew;
            float c0 = __shfl(corr, lg * 4 + 0);
            float c1 = __shfl(corr, lg * 4 + 1);
            float c2 = __shfl(corr, lg * 4 + 2);
            float c3 = __shfl(corr, lg * 4 + 3);
#pragma unroll
            for (int i = 0; i < 8; i++) {
                f32x4 t4 = o[i];
                t4[0] *= c0; t4[1] *= c1; t4[2] *= c2; t4[3] *= c3;
                o[i] = t4;
            }
        }

        // P = exp2(S - m), packed bf16 pairs into swizzled wave-private Pl rows
        float lsum = 0.0f;
#pragma unroll
        for (int nf = 0; nf < 4; nf++) {
            float p0 = EXP2(sc[nf][0] - m_run);
            float p1 = EXP2(sc[nf][1] - m_run);
            float p2 = EXP2(sc[nf][2] - m_run);
            float p3 = EXP2(sc[nf][3] - m_run);
            lsum += (p0 + p1) + (p2 + p3);
            *(u32a*)(pbase + ((nf * 32 + lg * 8) ^ sw))     = cvt_pk_bf16(p0, p1);
            *(u32a*)(pbase + ((nf * 32 + lg * 8 + 4) ^ sw)) = cvt_pk_bf16(p2, p3);
        }
        lsum += __shfl_xor(lsum, 16);
        lsum += __shfl_xor(lsum, 32);
        l_run = l_run * corr + lsum;

        // P A-fragment: lane holds P[q=ln][kv = kk*32+lg*8+j]
        bf16x8 pf[2];
#pragma unroll
        for (int kk = 0; kk < 2; kk++)
            pf[kk] = *(const bf16x8*)(pbase + ((kk * 64 + lg * 16) ^ sw));

        // PV: o[nf] covers d = nf*16+ln, q rows = lg*4+r
        __builtin_amdgcn_s_setprio(1);
#pragma unroll
        for (int nf = 0; nf < 8; nf++)
#pragma unroll
            for (int kk = 0; kk < 2; kk++) {
                int row = nf * 16 + ln;
                int cb = (kk * 64 + lg * 16) ^ ((row & 7) << 4);
                bf16x8 vf = *(const bf16x8*)((const char*)Vl[cur] + row * 128 + cb);
                o[nf] = __builtin_amdgcn_mfma_f32_16x16x32_bf16(pf[kk], vf, o[nf], 0, 0, 0);
            }
        __builtin_amdgcn_s_setprio(0);

        if (t < S_ / 64 - 1) __syncthreads();  // drains t+1 stages (overlapped w/ compute)
    }

    // normalize + store bf16: q = q0 + w*16 + lg*4 + r, d = nf*16 + ln
    float i0 = 1.0f / __shfl(l_run, lg * 4 + 0);
    float i1 = 1.0f / __shfl(l_run, lg * 4 + 1);
    float i2 = 1.0f / __shfl(l_run, lg * 4 + 2);
    float i3 = 1.0f / __shfl(l_run, lg * 4 + 3);
#pragma unroll
    for (int nf = 0; nf < 8; nf++) {
        int rowb = (b * S_ + q0 + w * 16 + lg * 4) * (H_ * HD_) + h * HD_ + nf * 16 + ln;
        attn_o[rowb]                 = f2bf(o[nf][0] * i0);
        attn_o[rowb + 1 * H_ * HD_]  = f2bf(o[nf][1] * i1);
        attn_o[rowb + 2 * H_ * HD_]  = f2bf(o[nf][2] * i2);
        attn_o[rowb + 3 * H_ * HD_]  = f2bf(o[nf][3] * i3);
    }
}

extern "C" void kernel_launch(void* const* d_in, const int* in_sizes, int n_in,
                              void* d_out, int out_size, void* d_ws, size_t ws_size,
                              hipStream_t stream) {
    const float* x    = (const float*)d_in[0];
    // d_in[1] = start_pos (always 0 for this problem)
    const float* fcos = (const float*)d_in[2];
    const float* fsin = (const float*)d_in[3];
    const float* wq   = (const float*)d_in[4];
    const float* wk   = (const float*)d_in[5];
    const float* wv   = (const float*)d_in[6];
    const float* wo   = (const float*)d_in[7];
    float* out = (float*)d_out;

    char* ws = (char*)d_ws;
    // workspace layout (bytes)
    u16* x_b    = (u16*)(ws);                    // 16,777,216  (aliased by attn_o later)
    u16* wqkv_b = (u16*)(ws + 16777216);         // 12,582,912
    u16* wo_b   = (u16*)(ws + 29360128);         //  8,388,608
    u16* xqkv_b = (u16*)(ws + 37748736);         // 25,165,824
    u16* xk_b   = (u16*)(ws + 62914560);         //  4,194,304
    u16* vt_b   = (u16*)(ws + 67108864);         //  4,194,304
    u16* attn_o = x_b;                           // reuse: x_b dead after QKV GEMM

    // 1. convert inputs to bf16
    cvt_f32_bf16<<<4096, 256, 0, stream>>>(x, x_b, (NTOK * DIM_) / 4);
    cvt_f32_bf16<<<2048, 256, 0, stream>>>(wq, wqkv_b, (2048 * 2048) / 4);
    cvt_f32_bf16<<<512, 256, 0, stream>>>(wk, wqkv_b + 2048 * 2048, (512 * 2048) / 4);
    cvt_f32_bf16<<<512, 256, 0, stream>>>(wv, wqkv_b + 2560 * 2048, (512 * 2048) / 4);
    cvt_f32_bf16<<<2048, 256, 0, stream>>>(wo, wo_b, (2048 * 2048) / 4);

    // 2. fused QKV GEMM: (4096 x 3072 x 2048), bf16 out, 8-phase 256^2, 192 blocks
    gemm256<1><<<(NTOK / 256) * (NQKV / 256), 512, 0, stream>>>(
        x_b, wqkv_b, xqkv_b, NTOK, NQKV, DIM_, NQKV / 256);

    // 3. RoPE (Q in place, K -> xk_b)
    rope_k<<<NTOK, 256, 0, stream>>>(xqkv_b, xk_b, fcos, fsin);

    // 4. V transpose -> (b,g,d,pos)
    vtrans<<<1024, 256, 0, stream>>>(xqkv_b, vt_b);

    // 5. attention: QBLK=128, 512 threads, 2 blocks/CU
    attn_kernel<<<dim3(S_ / 128, H_, B_), 512, 0, stream>>>(xqkv_b, xk_b, vt_b, attn_o);

    // 6. output projection: (4096 x 2048 x 2048), fp32 out, 8-phase 256^2, 128 blocks
    gemm256<0><<<(NTOK / 256) * (DIM_ / 256), 512, 0, stream>>>(
        attn_o, wo_b, out, NTOK, DIM_, DIM_, DIM_ / 256);
}